// Round 1
// baseline (126.388 us; speedup 1.0000x reference)
//
#include <hip/hip_runtime.h>
#include <hip/hip_bf16.h>
#include <math.h>

// SP_loss: s = X X^T / T (N=8192, D=256, T=0.04, groups of 4).
// loss = mean_g softplus((neg[g] - margin[g]) / T)
//   neg[g]    = T * log sum_{i in g, j not in group g} exp(s[i,j])   (bf16 MFMA GEMM, fused exp+rowsum, mask-in-loop)
//   margin[g] = from exact fp32 4x4 group Gram block (hard_pos / least_pos / alpha)

#define NROWS 8192
#define DDIM  256
#define NGRP  2048
#define T_CONST 0.04f
#define INV_T   25.0f

typedef __attribute__((ext_vector_type(8))) short bf16x8_t;
typedef __attribute__((ext_vector_type(4))) float f32x4_t;

typedef const __attribute__((address_space(1))) void gv_t;
typedef __attribute__((address_space(3))) void lv_t;

__device__ __forceinline__ unsigned short f2bf_rne(float f) {
    unsigned int u = __float_as_uint(f);
    unsigned int r = 0x7fffu + ((u >> 16) & 1u);
    return (unsigned short)((u + r) >> 16);
}

__device__ __forceinline__ void gll16(const unsigned short* g, unsigned short* l) {
    __builtin_amdgcn_global_load_lds((gv_t*)g, (lv_t*)l, 16, 0, 0);
}

// Kernel A: fp32 -> bf16 convert (RNE) + zero the rowsum accumulator (ws is poisoned each launch).
__global__ __launch_bounds__(256) void cvt_zero_kernel(const float* __restrict__ x,
                                                       unsigned short* __restrict__ xb,
                                                       float* __restrict__ rowsum) {
    int gid = blockIdx.x * 256 + threadIdx.x;
    int i = gid * 4;
    float4 v = *(const float4*)(x + i);
    ushort4 b;
    b.x = f2bf_rne(v.x); b.y = f2bf_rne(v.y); b.z = f2bf_rne(v.z); b.w = f2bf_rne(v.w);
    *(ushort4*)(xb + i) = b;
    if (gid < NROWS) rowsum[gid] = 0.f;
}

// Kernel B: per-group exact fp32 4x4 Gram -> margin[g]. One wave per group.
__global__ __launch_bounds__(64) void pos_margin_kernel(const float* __restrict__ x,
                                                        float* __restrict__ margin) {
    const int g = blockIdx.x;
    const int lane = threadIdx.x;
    const float* xr = x + (size_t)g * 4 * DDIM;
    float a[16];
#pragma unroll
    for (int k = 0; k < 16; ++k) a[k] = 0.f;
    for (int e = lane; e < DDIM; e += 64) {
        float vv[4];
        vv[0] = xr[e];
        vv[1] = xr[DDIM + e];
        vv[2] = xr[2 * DDIM + e];
        vv[3] = xr[3 * DDIM + e];
#pragma unroll
        for (int i = 0; i < 4; ++i)
#pragma unroll
            for (int j = 0; j < 4; ++j)
                a[i * 4 + j] = fmaf(vv[i], vv[j], a[i * 4 + j]);
    }
#pragma unroll
    for (int k = 0; k < 16; ++k) {
        float t = a[k];
        t += __shfl_xor(t, 32, 64);
        t += __shfl_xor(t, 16, 64);
        t += __shfl_xor(t, 8, 64);
        t += __shfl_xor(t, 4, 64);
        t += __shfl_xor(t, 2, 64);
        t += __shfl_xor(t, 1, 64);
        a[k] = t;
    }
    if (lane == 0) {
        float pos[16];
#pragma unroll
        for (int k = 0; k < 16; ++k) pos[k] = a[k] * INV_T;

        // hard_pos = -T * LSE_16(-pos)
        float mx = -pos[0];
#pragma unroll
        for (int k = 1; k < 16; ++k) mx = fmaxf(mx, -pos[k]);
        float se = 0.f;
#pragma unroll
        for (int k = 0; k < 16; ++k) se += __expf(-pos[k] - mx);
        float hard_pos = -T_CONST * (mx + __logf(se));

        // lse_row[i] = LSE_j(-pos[i][j]); least_pos = T * LSE_i(-lse_row[i])
        float lse_row[4];
#pragma unroll
        for (int i = 0; i < 4; ++i) {
            float m2 = -pos[i * 4];
#pragma unroll
            for (int j = 1; j < 4; ++j) m2 = fmaxf(m2, -pos[i * 4 + j]);
            float s2 = 0.f;
#pragma unroll
            for (int j = 0; j < 4; ++j) s2 += __expf(-pos[i * 4 + j] - m2);
            lse_row[i] = m2 + __logf(s2);
        }
        float m3 = -lse_row[0];
#pragma unroll
        for (int i = 1; i < 4; ++i) m3 = fmaxf(m3, -lse_row[i]);
        float s3 = 0.f;
#pragma unroll
        for (int i = 0; i < 4; ++i) s3 += __expf(-lse_row[i] - m3);
        float least_pos = T_CONST * (m3 + __logf(s3));

        float alpha = (hard_pos >= 0.f)
                          ? (2.f * least_pos * hard_pos) / (hard_pos + least_pos)
                          : 0.f;
        margin[g] = alpha * hard_pos + (1.f - alpha) * least_pos;
    }
}

// Kernel C: fused bf16 GEMM (s = X X^T / T) + exp + same-group mask + row-sum.
// m97 structure: 128x128 tile, BK=32, 4 waves of 4x4 16x16x32 MFMAs,
// global_load_lds width-16 staging, ds_read_b128 fragments.
__global__ __launch_bounds__(256) void gemm_exp_rowsum(const unsigned short* __restrict__ xb,
                                                       float* __restrict__ rowsum) {
    __shared__ unsigned short Als[128 * 32];
    __shared__ unsigned short Bls[128 * 32];
    __shared__ float rowacc[128];

    const int tid = threadIdx.x;
    const int lane = tid & 63;
    const int w = tid >> 6;
    const int row0 = blockIdx.y * 128;
    const int col0 = blockIdx.x * 128;
    const int wrow = (w >> 1) * 64;
    const int wcol = (w & 1) * 64;
    const int quad = lane >> 4;
    const int l16 = lane & 15;
    const int srow = tid >> 2;          // staging row 0..63
    const int scol = (tid & 3) * 8;     // staging k-offset (elements)

    if (tid < 128) rowacc[tid] = 0.f;

    f32x4_t acc[4][4];
#pragma unroll
    for (int i = 0; i < 4; ++i)
#pragma unroll
        for (int j = 0; j < 4; ++j)
            acc[i][j] = (f32x4_t){0.f, 0.f, 0.f, 0.f};

    const unsigned short* ga = xb + (size_t)(row0 + srow) * DDIM + scol;
    const unsigned short* gb = xb + (size_t)(col0 + srow) * DDIM + scol;

    for (int kb = 0; kb < DDIM; kb += 32) {
        if (kb) __syncthreads();   // previous iter's readers done before overwrite
        gll16(ga + kb,              &Als[tid * 8]);
        gll16(ga + kb + 64 * DDIM,  &Als[2048 + tid * 8]);
        gll16(gb + kb,              &Bls[tid * 8]);
        gll16(gb + kb + 64 * DDIM,  &Bls[2048 + tid * 8]);
        __syncthreads();           // barrier drains vmcnt -> LDS tiles ready

        bf16x8_t aF[4], bF[4];
#pragma unroll
        for (int mi = 0; mi < 4; ++mi)
            aF[mi] = *(const bf16x8_t*)&Als[(wrow + mi * 16 + l16) * 32 + quad * 8];
#pragma unroll
        for (int ni = 0; ni < 4; ++ni)
            bF[ni] = *(const bf16x8_t*)&Bls[(wcol + ni * 16 + l16) * 32 + quad * 8];
#pragma unroll
        for (int mi = 0; mi < 4; ++mi)
#pragma unroll
            for (int ni = 0; ni < 4; ++ni)
                acc[mi][ni] = __builtin_amdgcn_mfma_f32_16x16x32_bf16(aF[mi], bF[ni],
                                                                      acc[mi][ni], 0, 0, 0);
    }

    // Epilogue: C/D layout col=lane&15, row=quad*4+reg. exp + same-group mask,
    // sum over ni in-register, over the 16 col-lanes via shfl, then LDS/global atomics.
#pragma unroll
    for (int mi = 0; mi < 4; ++mi) {
#pragma unroll
        for (int reg = 0; reg < 4; ++reg) {
            const int lrow = wrow + mi * 16 + quad * 4 + reg;
            const int grp = (row0 + lrow) >> 2;
            float v = 0.f;
#pragma unroll
            for (int ni = 0; ni < 4; ++ni) {
                const int gcol = col0 + wcol + ni * 16 + l16;
                const float sv = acc[mi][ni][reg] * INV_T;
                v += ((gcol >> 2) == grp) ? 0.f : __expf(sv);
            }
            v += __shfl_xor(v, 1, 64);
            v += __shfl_xor(v, 2, 64);
            v += __shfl_xor(v, 4, 64);
            v += __shfl_xor(v, 8, 64);
            if (l16 == 0) atomicAdd(&rowacc[lrow], v);
        }
    }
    __syncthreads();
    if (tid < 128) atomicAdd(&rowsum[row0 + tid], rowacc[tid]);
}

// Kernel D: neg[g] = T*log(sum of 4 row sums); loss = mean softplus((neg-margin)/T).
__global__ __launch_bounds__(256) void finalize_kernel(const float* __restrict__ rowsum,
                                                       const float* __restrict__ margin,
                                                       float* __restrict__ out) {
    const int tid = threadIdx.x;
    float local = 0.f;
    for (int g = tid; g < NGRP; g += 256) {
        float s = rowsum[4 * g] + rowsum[4 * g + 1] + rowsum[4 * g + 2] + rowsum[4 * g + 3];
        float z = __logf(s) - margin[g] * INV_T;   // (neg - margin)/T
        float sp = (z > 30.f) ? z : log1pf(__expf(z));
        local += sp;
    }
    local += __shfl_xor(local, 1, 64);
    local += __shfl_xor(local, 2, 64);
    local += __shfl_xor(local, 4, 64);
    local += __shfl_xor(local, 8, 64);
    local += __shfl_xor(local, 16, 64);
    local += __shfl_xor(local, 32, 64);
    __shared__ float wsum[4];
    if ((tid & 63) == 0) wsum[tid >> 6] = local;
    __syncthreads();
    if (tid == 0) out[0] = (wsum[0] + wsum[1] + wsum[2] + wsum[3]) * (1.f / (float)NGRP);
}

extern "C" void kernel_launch(void* const* d_in, const int* in_sizes, int n_in,
                              void* d_out, int out_size, void* d_ws, size_t ws_size,
                              hipStream_t stream) {
    const float* x = (const float*)d_in[0];
    float* out = (float*)d_out;

    unsigned short* xb = (unsigned short*)d_ws;                              // 4 MiB bf16 X
    float* rowsum = (float*)((char*)d_ws + (size_t)NROWS * DDIM * 2);        // 32 KiB
    float* margin = rowsum + NROWS;                                          // 8 KiB

    cvt_zero_kernel<<<(NROWS * DDIM / 4) / 256, 256, 0, stream>>>(x, xb, rowsum);
    pos_margin_kernel<<<NGRP, 64, 0, stream>>>(x, margin);
    gemm_exp_rowsum<<<dim3(64, 64), 256, 0, stream>>>(xb, rowsum);
    finalize_kernel<<<1, 256, 0, stream>>>(rowsum, margin, out);
}

// Round 2
// 116.455 us; speedup vs baseline: 1.0853x; 1.0853x over previous
//
#include <hip/hip_runtime.h>
#include <hip/hip_bf16.h>
#include <math.h>

// SP_loss: s = X X^T / T (N=8192, D=256, T=0.04, groups of 4).
// loss = mean_g softplus((neg[g] - margin[g]) / T)
//   neg[g]    = T * log sum_{i in g, j not in g} exp(s[i,j])
//               -> symmetric bf16 MFMA GEMM over upper-tri 128x128 tiles,
//                  fused exp + row-sum (+ col-sum for off-diag tiles).
//   margin[g] = exact fp32 4x4 group Gram block (hard_pos / least_pos / alpha)

#define NROWS 8192
#define DDIM  256
#define NGRP  2048
#define NTB   64          // 8192 / 128 tile-blocks per dim
#define T_CONST 0.04f
#define INV_T   25.0f

typedef __attribute__((ext_vector_type(8))) short bf16x8_t;
typedef __attribute__((ext_vector_type(4))) float f32x4_t;

typedef const __attribute__((address_space(1))) void gv_t;
typedef __attribute__((address_space(3))) void lv_t;

__device__ __forceinline__ unsigned short f2bf_rne(float f) {
    unsigned int u = __float_as_uint(f);
    unsigned int r = 0x7fffu + ((u >> 16) & 1u);
    return (unsigned short)((u + r) >> 16);
}

__device__ __forceinline__ void gll16(const unsigned short* g, unsigned short* l) {
    __builtin_amdgcn_global_load_lds((gv_t*)g, (lv_t*)l, 16, 0, 0);
}

// Kernel A (fused prep): blocks 0..2047 convert fp32->bf16 (RNE) + zero rowsum;
// blocks 2048..2559 compute margin[g] (4 groups per block, one wave each).
__global__ __launch_bounds__(256) void prep_kernel(const float* __restrict__ x,
                                                   unsigned short* __restrict__ xb,
                                                   float* __restrict__ rowsum,
                                                   float* __restrict__ margin) {
    const int b = blockIdx.x;
    if (b < 2048) {
        int gid = b * 256 + threadIdx.x;
        int i = gid * 4;
        float4 v = *(const float4*)(x + i);
        ushort4 o;
        o.x = f2bf_rne(v.x); o.y = f2bf_rne(v.y); o.z = f2bf_rne(v.z); o.w = f2bf_rne(v.w);
        *(ushort4*)(xb + i) = o;
        if (gid < NROWS) rowsum[gid] = 0.f;
        return;
    }
    const int g = (b - 2048) * 4 + (threadIdx.x >> 6);
    const int lane = threadIdx.x & 63;
    const float* xr = x + (size_t)g * 4 * DDIM;
    float a[16];
#pragma unroll
    for (int k = 0; k < 16; ++k) a[k] = 0.f;
    for (int e = lane; e < DDIM; e += 64) {
        float vv[4];
        vv[0] = xr[e];
        vv[1] = xr[DDIM + e];
        vv[2] = xr[2 * DDIM + e];
        vv[3] = xr[3 * DDIM + e];
#pragma unroll
        for (int i = 0; i < 4; ++i)
#pragma unroll
            for (int j = 0; j < 4; ++j)
                a[i * 4 + j] = fmaf(vv[i], vv[j], a[i * 4 + j]);
    }
#pragma unroll
    for (int k = 0; k < 16; ++k) {
        float t = a[k];
        t += __shfl_xor(t, 32, 64);
        t += __shfl_xor(t, 16, 64);
        t += __shfl_xor(t, 8, 64);
        t += __shfl_xor(t, 4, 64);
        t += __shfl_xor(t, 2, 64);
        t += __shfl_xor(t, 1, 64);
        a[k] = t;
    }
    if (lane == 0) {
        float pos[16];
#pragma unroll
        for (int k = 0; k < 16; ++k) pos[k] = a[k] * INV_T;

        float mx = -pos[0];
#pragma unroll
        for (int k = 1; k < 16; ++k) mx = fmaxf(mx, -pos[k]);
        float se = 0.f;
#pragma unroll
        for (int k = 0; k < 16; ++k) se += __expf(-pos[k] - mx);
        float hard_pos = -T_CONST * (mx + __logf(se));

        float lse_row[4];
#pragma unroll
        for (int i = 0; i < 4; ++i) {
            float m2 = -pos[i * 4];
#pragma unroll
            for (int j = 1; j < 4; ++j) m2 = fmaxf(m2, -pos[i * 4 + j]);
            float s2 = 0.f;
#pragma unroll
            for (int j = 0; j < 4; ++j) s2 += __expf(-pos[i * 4 + j] - m2);
            lse_row[i] = m2 + __logf(s2);
        }
        float m3 = -lse_row[0];
#pragma unroll
        for (int i = 1; i < 4; ++i) m3 = fmaxf(m3, -lse_row[i]);
        float s3 = 0.f;
#pragma unroll
        for (int i = 0; i < 4; ++i) s3 += __expf(-lse_row[i] - m3);
        float least_pos = T_CONST * (m3 + __logf(s3));

        float alpha = (hard_pos >= 0.f)
                          ? (2.f * least_pos * hard_pos) / (hard_pos + least_pos)
                          : 0.f;
        margin[g] = alpha * hard_pos + (1.f - alpha) * least_pos;
    }
}

// Kernel B: symmetric fused bf16 GEMM. Upper-triangular tiles only (2080 blocks).
// 128x128 tile, BK=32, 4 waves of 4x4 16x16x32 MFMAs, global_load_lds width-16,
// XOR-swizzled LDS layout: chunk (row,kc) stored at row*32 + (kc^((row>>1)&3))*8
// -> fragment ds_read_b128 is 2-way (free) instead of 8-way per 16-lane phase.
// Off-diag tiles (bi<bj): groups disjoint, no mask; exp feeds rowsum[row] AND
// rowsum[col] (s symmetric, identical dot). Diag tiles: same-group mask, rows only.
__global__ __launch_bounds__(256) void gemm_exp_rowsum(const unsigned short* __restrict__ xb,
                                                       float* __restrict__ rowsum) {
    __shared__ unsigned short Als[128 * 32];
    __shared__ unsigned short Bls[128 * 32];
    __shared__ float rowacc[128];
    __shared__ float colacc[128];

    // decode upper-triangular (bi, bj), bi <= bj, row-major: offset(bi)=bi*(129-bi)/2
    const int idx = blockIdx.x;
    int bi = (int)((129.0f - sqrtf(16641.0f - 8.0f * (float)idx)) * 0.5f);
    while (bi * (129 - bi) / 2 > idx) --bi;
    while ((bi + 1) * (128 - bi) / 2 <= idx) ++bi;
    const int bj = bi + (idx - bi * (129 - bi) / 2);
    const int row0 = bi * 128;
    const int col0 = bj * 128;
    const bool diag = (bi == bj);

    const int tid = threadIdx.x;
    const int lane = tid & 63;
    const int w = tid >> 6;
    const int wrow = (w >> 1) * 64;
    const int wcol = (w & 1) * 64;
    const int quad = lane >> 4;
    const int l16 = lane & 15;
    const int swz = (l16 >> 1) & 3;
    const int srow = tid >> 2;                       // staging row 0..63
    const int kc = (tid & 3) ^ ((tid >> 3) & 3);     // swizzled global k-chunk

    if (tid < 128) { rowacc[tid] = 0.f; colacc[tid] = 0.f; }

    f32x4_t acc[4][4];
#pragma unroll
    for (int i = 0; i < 4; ++i)
#pragma unroll
        for (int j = 0; j < 4; ++j)
            acc[i][j] = (f32x4_t){0.f, 0.f, 0.f, 0.f};

    const unsigned short* ga = xb + (size_t)(row0 + srow) * DDIM + kc * 8;
    const unsigned short* gb = xb + (size_t)(col0 + srow) * DDIM + kc * 8;

    for (int kb = 0; kb < DDIM; kb += 32) {
        if (kb) __syncthreads();
        gll16(ga + kb,             &Als[tid * 8]);
        gll16(ga + kb + 64 * DDIM, &Als[2048 + tid * 8]);
        gll16(gb + kb,             &Bls[tid * 8]);
        gll16(gb + kb + 64 * DDIM, &Bls[2048 + tid * 8]);
        __syncthreads();

        bf16x8_t aF[4], bF[4];
#pragma unroll
        for (int mi = 0; mi < 4; ++mi)
            aF[mi] = *(const bf16x8_t*)&Als[(wrow + mi * 16 + l16) * 32 + (quad ^ swz) * 8];
#pragma unroll
        for (int ni = 0; ni < 4; ++ni)
            bF[ni] = *(const bf16x8_t*)&Bls[(wcol + ni * 16 + l16) * 32 + (quad ^ swz) * 8];
#pragma unroll
        for (int mi = 0; mi < 4; ++mi)
#pragma unroll
            for (int ni = 0; ni < 4; ++ni)
                acc[mi][ni] = __builtin_amdgcn_mfma_f32_16x16x32_bf16(aF[mi], bF[ni],
                                                                      acc[mi][ni], 0, 0, 0);
    }

    // Epilogue. C/D layout: col = wcol + ni*16 + l16, row = wrow + mi*16 + quad*4 + reg.
    if (!diag) {
        float colv[4] = {0.f, 0.f, 0.f, 0.f};
#pragma unroll
        for (int mi = 0; mi < 4; ++mi) {
#pragma unroll
            for (int reg = 0; reg < 4; ++reg) {
                const int lrow = wrow + mi * 16 + quad * 4 + reg;
                float rv = 0.f;
#pragma unroll
                for (int ni = 0; ni < 4; ++ni) {
                    float e = __expf(acc[mi][ni][reg] * INV_T);
                    rv += e;
                    colv[ni] += e;
                }
                rv += __shfl_xor(rv, 1, 64);
                rv += __shfl_xor(rv, 2, 64);
                rv += __shfl_xor(rv, 4, 64);
                rv += __shfl_xor(rv, 8, 64);
                if (l16 == 0) atomicAdd(&rowacc[lrow], rv);
            }
        }
#pragma unroll
        for (int ni = 0; ni < 4; ++ni) {
            float cv = colv[ni];
            cv += __shfl_xor(cv, 16, 64);
            cv += __shfl_xor(cv, 32, 64);
            if (quad == 0) atomicAdd(&colacc[wcol + ni * 16 + l16], cv);
        }
    } else {
#pragma unroll
        for (int mi = 0; mi < 4; ++mi) {
#pragma unroll
            for (int reg = 0; reg < 4; ++reg) {
                const int lrow = wrow + mi * 16 + quad * 4 + reg;
                const int grp = (row0 + lrow) >> 2;
                float rv = 0.f;
#pragma unroll
                for (int ni = 0; ni < 4; ++ni) {
                    const int gcol = col0 + wcol + ni * 16 + l16;
                    rv += ((gcol >> 2) == grp) ? 0.f : __expf(acc[mi][ni][reg] * INV_T);
                }
                rv += __shfl_xor(rv, 1, 64);
                rv += __shfl_xor(rv, 2, 64);
                rv += __shfl_xor(rv, 4, 64);
                rv += __shfl_xor(rv, 8, 64);
                if (l16 == 0) atomicAdd(&rowacc[lrow], rv);
            }
        }
    }
    __syncthreads();
    if (tid < 128) {
        atomicAdd(&rowsum[row0 + tid], rowacc[tid]);
        if (!diag) atomicAdd(&rowsum[col0 + tid], colacc[tid]);
    }
}

// Kernel C: neg[g] = T*log(sum of 4 row sums); loss = mean softplus((neg-margin)/T).
__global__ __launch_bounds__(256) void finalize_kernel(const float* __restrict__ rowsum,
                                                       const float* __restrict__ margin,
                                                       float* __restrict__ out) {
    const int tid = threadIdx.x;
    float local = 0.f;
    for (int g = tid; g < NGRP; g += 256) {
        float s = rowsum[4 * g] + rowsum[4 * g + 1] + rowsum[4 * g + 2] + rowsum[4 * g + 3];
        float z = __logf(s) - margin[g] * INV_T;   // (neg - margin)/T
        float sp = (z > 30.f) ? z : log1pf(__expf(z));
        local += sp;
    }
    local += __shfl_xor(local, 1, 64);
    local += __shfl_xor(local, 2, 64);
    local += __shfl_xor(local, 4, 64);
    local += __shfl_xor(local, 8, 64);
    local += __shfl_xor(local, 16, 64);
    local += __shfl_xor(local, 32, 64);
    __shared__ float wsum[4];
    if ((tid & 63) == 0) wsum[tid >> 6] = local;
    __syncthreads();
    if (tid == 0) out[0] = (wsum[0] + wsum[1] + wsum[2] + wsum[3]) * (1.f / (float)NGRP);
}

extern "C" void kernel_launch(void* const* d_in, const int* in_sizes, int n_in,
                              void* d_out, int out_size, void* d_ws, size_t ws_size,
                              hipStream_t stream) {
    const float* x = (const float*)d_in[0];
    float* out = (float*)d_out;

    unsigned short* xb = (unsigned short*)d_ws;                              // 4 MiB bf16 X
    float* rowsum = (float*)((char*)d_ws + (size_t)NROWS * DDIM * 2);        // 32 KiB
    float* margin = rowsum + NROWS;                                          // 8 KiB

    prep_kernel<<<2048 + 512, 256, 0, stream>>>(x, xb, rowsum, margin);
    gemm_exp_rowsum<<<NTB * (NTB + 1) / 2, 256, 0, stream>>>(xb, rowsum);
    finalize_kernel<<<1, 256, 0, stream>>>(rowsum, margin, out);
}